// Round 10
// baseline (356.876 us; speedup 1.0000x reference)
//
#include <hip/hip_runtime.h>
#include <math.h>

// Problem constants
#define NA    50
#define NT    50
#define HIDK  128
#define NH    32
#define NC    16
#define NB    32
#define SAT   2500    // NA*NT
#define NS    2450    // (NA-1)*NT
#define NOUT  512     // NH*NC

// ============ K0: PQ[j][k] = sum_c att[j][c] * W[(j%32)*16+c][k] ============
__global__ __launch_bounds__(256) void k0_pq(const float* __restrict__ W,
                                             const float* __restrict__ att_src,
                                             const float* __restrict__ att_dst,
                                             float* __restrict__ PQ) {
  int g = blockIdx.x * 256 + threadIdx.x;   // 8192 total
  int j = g >> 7, k = g & 127;
  int hh = j & 31;
  const float* att = (j < 32) ? att_src : att_dst;
  float acc = 0.f;
  #pragma unroll
  for (int c = 0; c < 16; ++c)
    acc = fmaf(att[hh * 16 + c], W[(size_t)(hh * 16 + c) * 128 + k], acc);
  PQ[g] = acc;
}

// ============ K1: u[b][h][s] = x_row . p_h ; d[b][h][t] = x_ego_row . q_h ============
// k1 is permanent (R15 lesson: fusing re-reads X 32x from L2, bad trade).
__global__ __launch_bounds__(256) void k1_ud(
    const float* __restrict__ X,     // (80000,128)
    const float* __restrict__ PQ,    // (64,128)
    float* __restrict__ u,           // [b][h][2500]
    float* __restrict__ dv)          // [b][h][50]
{
  __shared__ float Ast[32][68];
  __shared__ float Bst[32][68];
  const int tid = threadIdx.x;
  const int m0 = blockIdx.x * 64;
  const int ty = tid >> 4, tx = tid & 15;
  float acc[4][4] = {};
  const int sr = tid >> 3, sc = tid & 7;

  for (int kc = 0; kc < 128; kc += 32) {
    #pragma unroll
    for (int L = 0; L < 2; ++L) {
      int row = sr + L * 32;
      float4 v = *(const float4*)&X[(size_t)(m0 + row) * 128 + kc + sc * 4];
      Ast[sc*4+0][row] = v.x; Ast[sc*4+1][row] = v.y;
      Ast[sc*4+2][row] = v.z; Ast[sc*4+3][row] = v.w;
      float4 w = *(const float4*)&PQ[(size_t)row * 128 + kc + sc * 4];
      Bst[sc*4+0][row] = w.x; Bst[sc*4+1][row] = w.y;
      Bst[sc*4+2][row] = w.z; Bst[sc*4+3][row] = w.w;
    }
    __syncthreads();
    #pragma unroll
    for (int k = 0; k < 32; ++k) {
      float4 a4 = *(const float4*)&Ast[k][ty * 4];
      float4 b4 = *(const float4*)&Bst[k][tx * 4];
      float a[4] = {a4.x, a4.y, a4.z, a4.w};
      float bb[4] = {b4.x, b4.y, b4.z, b4.w};
      #pragma unroll
      for (int i = 0; i < 4; ++i)
        #pragma unroll
        for (int j = 0; j < 4; ++j)
          acc[i][j] = fmaf(a[i], bb[j], acc[i][j]);
    }
    __syncthreads();
  }

  #pragma unroll
  for (int i = 0; i < 4; ++i) {
    int m = m0 + ty * 4 + i;
    int b = m / SAT, s = m - b * SAT;
    #pragma unroll
    for (int jj = 0; jj < 4; ++jj) {
      int col = tx * 4 + jj;
      if (col < 32)
        u[(size_t)(b * 32 + col) * SAT + s] = acc[i][jj];
      else if (s < NT)
        dv[(size_t)(b * 32 + col - 32) * NT + s] = acc[i][jj];
    }
  }
}

// ============ K2: bucket-decomposed attention in x-space ============
// R17: base = R16 (291.9us best; LPT stealing +20us confirmed). New: P-space
// projection. The post-F pipeline was {129-ch scans: 258 threads x 51-long
// serial LDS chains} + {epilogue: 800 tasks x 256 scalar LDS reads}. By
// linearity (sum_k Bb[k])*W == sum_k (Bb[k]*W): project per-BUCKET first
// (P[s][k][cout] = Bb[s][k][.]*W_h[cout], same FLOPs as old epilogue), then
// scan 34 chains (2x17) instead of 258, epilogue = 6 ops/task. Enablers:
// Bb rows padded 129->132 (16B-aligned -> float4 LDS reads, 32/task);
// WshT staging deleted (W_h=8KB read direct, L1-resident). LDS 78.8->80.0KB,
// still <=81.9KB -> 2 blocks/CU preserved (256B granule, ~1.9KB margin).
#define BBW 132   // padded Bb row (floats); z at index 128

#define LOADG(B_, g_) do {                                                  \
    _Pragma("unroll")                                                       \
    for (int j = 0; j < 4; ++j) {                                           \
      int idx_ = base + 2 * ((g_) * 4 + j);                                 \
      e##B_[j] = sE[idx_]; s##B_[j] = sIdx[idx_];                           \
    }                                                                       \
    _Pragma("unroll")                                                       \
    for (int j = 0; j < 4; ++j)                                             \
      x##B_[j] = *(const float4*)(xb + (size_t)s##B_[j] * HIDK);            \
  } while (0)

#define COMPG(B_) do {                                                      \
    _Pragma("unroll")                                                       \
    for (int j = 0; j < 4; ++j) {                                           \
      float2 ee = e##B_[j]; float4 xx = x##B_[j];                           \
      a1[0]=fmaf(ee.x,xx.x,a1[0]); a1[1]=fmaf(ee.x,xx.y,a1[1]);             \
      a1[2]=fmaf(ee.x,xx.z,a1[2]); a1[3]=fmaf(ee.x,xx.w,a1[3]);             \
      a2[0]=fmaf(ee.y,xx.x,a2[0]); a2[1]=fmaf(ee.y,xx.y,a2[1]);             \
      a2[2]=fmaf(ee.y,xx.z,a2[2]); a2[3]=fmaf(ee.y,xx.w,a2[3]);             \
      z1 += ee.x; z2 += ee.y;                                               \
    }                                                                       \
  } while (0)

#define PP(s,k,c) Pa[(((s)*51+(k))*17)+(c)]

__global__ __launch_bounds__(512, 4) void k2_attn(
    const float* __restrict__ X,     // (32,2500,128)
    const float* __restrict__ u,     // [b][h][2500]
    const float* __restrict__ dv,    // [b][h][50]
    const float* __restrict__ W,     // (512,128)
    const float* __restrict__ bias,  // (512)
    float* __restrict__ out)
{
  const int id = blockIdx.x;
  const int b  = (id & 7) + 8 * (id >> 8);   // <=2 X-slices per XCD L2 window
  const int h  = (id >> 3) & 31;
  const int tid = threadIdx.x;

  __shared__ float Bb[2][51][BBW];   // [which][bucket][c]; c==128 = z   53.9 KB
  __shared__ float2 sE[NS];          // sorted (e1,e2)                   19.6 KB
  __shared__ unsigned short sIdx[NS];// sorted sat-index                  4.9 KB
  __shared__ float sTheta[50], sD[50], sF1[50], sF2[50];
  __shared__ int   sRank[50];
  __shared__ int   offs[52];
  __shared__ int   offCur[51];
  __shared__ int   segOrder[51];
  __shared__ int   segCtr;
  __shared__ float red[8];
  __shared__ float sMaxU;

  float* sU = &Bb[0][0][0];                       // alias (dead before F)
  unsigned short* sBeta = (unsigned short*)&Bb[1][0][0];  // alias (dead before F)
  float* Pa = (float*)sE;                         // P[2][51][17] alias (sE dead after F)

  const size_t bh = (size_t)b * 32 + h;
  const float* uP = u + bh * SAT + NT;   // skip ego rows

  // ---- load u (+ fused running max), dv ----
  float mx = -1e30f;
  for (int i = tid; i < NS; i += 512) { float v = uP[i]; sU[i] = v; mx = fmaxf(mx, v); }
  if (tid < 50) sD[tid] = dv[bh * NT + tid];
  if (tid < 51) offCur[tid] = 0;
  #pragma unroll
  for (int o = 32; o; o >>= 1) mx = fmaxf(mx, __shfl_xor(mx, o));
  if ((tid & 63) == 0) red[tid >> 6] = mx;
  __syncthreads();
  if (tid == 0) {
    float m2 = red[0];
    #pragma unroll
    for (int k = 1; k < 8; ++k) m2 = fmaxf(m2, red[k]);
    sMaxU = m2;
  }
  __syncthreads();
  const float maxU = sMaxU;

  // ---- theta rank-sort + per-query factors ----
  if (tid < 50) {
    float th = -sD[tid];
    int r = 0;
    for (int t2 = 0; t2 < 50; ++t2) {
      float th2 = -sD[t2];
      r += (th2 < th) || (th2 == th && t2 < tid);
    }
    sRank[tid] = r;
    sTheta[r] = th;
    float x = maxU + sD[tid];
    float L = (x >= 0.f) ? x : 0.2f * x;
    sF1[tid] = __expf(x - L);
    sF2[tid] = __expf(0.2f * x - L);
  }
  __syncthreads();

  // ---- histogram (store beta once; reuse in scatter) ----
  for (int i = tid; i < NS; i += 512) {
    float uu = sU[i];
    int lo = 0, hi = 50;
    while (lo < hi) { int mid = (lo + hi) >> 1; if (sTheta[mid] <= uu) lo = mid + 1; else hi = mid; }
    sBeta[i] = (unsigned short)lo;
    atomicAdd(&offCur[lo], 1);
  }
  __syncthreads();

  // ---- wave-0 parallel exclusive scan of 51 counts -> offs + offCur seed ----
  if (tid < 64) {
    int c = (tid < 51) ? offCur[tid] : 0;
    int inc = c;
    #pragma unroll
    for (int o = 1; o < 64; o <<= 1) {
      int n = __shfl_up(inc, o);
      if (tid >= o) inc += n;
    }
    if (tid < 51) { int ex = inc - c; offs[tid] = ex; offCur[tid] = ex; }
    if (tid == 50) offs[51] = inc;   // total = 2450
  }
  __syncthreads();

  // ---- scatter (all threads) + LPT segment sort (tid<51, overlapped) ----
  if (tid < 51) {
    int sz = offs[tid + 1] - offs[tid];
    int r = 0;
    for (int t2 = 0; t2 < 51; ++t2) {
      int sz2 = offs[t2 + 1] - offs[t2];
      r += (sz2 > sz) || (sz2 == sz && t2 < tid);
    }
    segOrder[r] = tid;    // descending size
  }
  if (tid == 511) segCtr = 0;
  for (int i = tid; i < NS; i += 512) {
    float uu = sU[i];
    int beta = sBeta[i];
    int pos = atomicAdd(&offCur[beta], 1);
    sE[pos] = make_float2(__expf(uu - maxU), __expf(0.2f * (uu - maxU)));
    sIdx[pos] = (unsigned short)(i + NT);
  }
  __syncthreads();

  // ---- F: LPT work-stealing, depth-2 software-pipelined gather ----
  {
    const int lane = tid & 63;
    const int slot = lane >> 5;       // which source of the pair
    const int cq   = lane & 31;       // channel quad cq*4..+3
    const float* xb = X + (size_t)b * SAT * HIDK + cq * 4;

    for (;;) {
      int kidx = 0;
      if (lane == 0) kidx = atomicAdd(&segCtr, 1);
      kidx = __shfl(kidx, 0);
      if (kidx >= 51) break;
      const int seg = segOrder[kidx];

      const int i0 = offs[seg], i1 = offs[seg + 1];
      const int base = i0 + slot;
      int np = i1 - base;                 // pairs this slot owns
      np = (np > 0) ? ((np + 1) >> 1) : 0;
      const int G = np >> 2;              // full groups of 4 pairs

      float a1[4] = {0.f, 0.f, 0.f, 0.f};
      float a2[4] = {0.f, 0.f, 0.f, 0.f};
      float z1 = 0.f, z2 = 0.f;

      float2 eA[4], eB[4]; int sA[4], sB[4]; float4 xA[4], xB[4];
      int g = 0;
      if (G) LOADG(A, 0);
      while (g + 2 <= G) {
        LOADG(B, g + 1);                  // prefetch next while computing cur
        COMPG(A);
        if (g + 2 < G) LOADG(A, g + 2);
        COMPG(B);
        g += 2;
      }
      if (g < G) COMPG(A);
      for (int k = G * 4; k < np; ++k) {  // remainder pairs
        int idx = base + 2 * k;
        float2 ee = sE[idx];
        int ss = sIdx[idx];
        float4 xx = *(const float4*)(xb + (size_t)ss * HIDK);
        a1[0]=fmaf(ee.x,xx.x,a1[0]); a1[1]=fmaf(ee.x,xx.y,a1[1]);
        a1[2]=fmaf(ee.x,xx.z,a1[2]); a1[3]=fmaf(ee.x,xx.w,a1[3]);
        a2[0]=fmaf(ee.y,xx.x,a2[0]); a2[1]=fmaf(ee.y,xx.y,a2[1]);
        a2[2]=fmaf(ee.y,xx.z,a2[2]); a2[3]=fmaf(ee.y,xx.w,a2[3]);
        z1 += ee.x; z2 += ee.y;
      }

      // combine the two slots; exclusive flush (no atomics, no zero-init)
      #pragma unroll
      for (int j = 0; j < 4; ++j) {
        a1[j] += __shfl_xor(a1[j], 32);
        a2[j] += __shfl_xor(a2[j], 32);
      }
      z1 += __shfl_xor(z1, 32);
      z2 += __shfl_xor(z2, 32);
      if (slot == 0) {
        #pragma unroll
        for (int j = 0; j < 4; ++j) {
          Bb[0][seg][cq * 4 + j] = a1[j];
          Bb[1][seg][cq * 4 + j] = a2[j];
        }
        if (cq == 0) { Bb[0][seg][128] = z1; Bb[1][seg][128] = z2; }
      }
    }
  }
  __syncthreads();

  // ---- P-space projection: P[s][k][cout] = Bb[s][k][.]*W_h[cout]; z copied ----
  // 16 lanes share each Bb row (broadcast); W_h rows (8KB) L1-resident.
  for (int task = tid; task < 1734; task += 512) {
    int s = task >= 867;
    int rem = task - s * 867;
    int k = rem / 17, cout = rem - k * 17;
    if (cout == 16) {
      PP(s, k, 16) = Bb[s][k][128];
    } else {
      const float4* br = (const float4*)&Bb[s][k][0];
      const float4* wr = (const float4*)&W[(size_t)(h * 16 + cout) * 128];
      float acc = 0.f;
      #pragma unroll
      for (int c4 = 0; c4 < 32; ++c4) {
        float4 bv = br[c4], wv = wr[c4];
        acc = fmaf(bv.x, wv.x, fmaf(bv.y, wv.y, fmaf(bv.z, wv.z, fmaf(bv.w, wv.w, acc))));
      }
      PP(s, k, cout) = acc;
    }
  }
  __syncthreads();

  // ---- scans over P: s=0 exclusive suffix, s=1 inclusive prefix (34 chains) ----
  if (tid < 34) {
    int s = tid >= 17;
    int cout = tid - s * 17;
    if (s == 0) {
      float run = 0.f;
      for (int k = 50; k >= 0; --k) { float tmp = PP(0, k, cout); PP(0, k, cout) = run; run += tmp; }
    } else {
      float run = 0.f;
      for (int k = 0; k <= 50; ++k) { run += PP(1, k, cout); PP(1, k, cout) = run; }
    }
  }
  __syncthreads();

  // ---- epilogue: combine, divide, bias, store ego slice (trivial now) ----
  for (int task = tid; task < NT * NC; task += 512) {
    int t = task >> 4, cout = task & 15;
    int r = sRank[t];
    float F1 = sF1[t], F2 = sF2[t];
    float z = F1 * PP(0, r, 16) + F2 * PP(1, r, 16);
    float n = F1 * PP(0, r, cout) + F2 * PP(1, r, cout);
    out[((size_t)b * SAT + t) * NOUT + h * 16 + cout] = n / z + bias[h * 16 + cout];
  }

  // ---- fused bias fill of the non-ego region: fire-and-forget tail stores ----
  // 1024 blocks x 9800 float4 == 32 b x 313600 float4 (rows a>=1). Disjoint
  // from every block's ego-slice writes (a==0), so no barrier/race; stores
  // drain while other resident blocks compute. (proven R8-R16)
  {
    int g0 = id * 9800 + tid;
    const float4 b4 = ((const float4*)bias)[g0 & 127];  // constant per thread (stride 512 ≡ 0 mod 128)
    float4* o4 = (float4*)out;
    int gEnd = (id + 1) * 9800;
    for (int g = g0; g < gEnd; g += 512) {
      int bb2 = g / 313600;
      int o = g - bb2 * 313600;
      o4[(size_t)bb2 * 320000 + 6400 + o] = b4;
    }
  }
}

extern "C" void kernel_launch(void* const* d_in, const int* in_sizes, int n_in,
                              void* d_out, int out_size, void* d_ws, size_t ws_size,
                              hipStream_t stream) {
  const float* X       = (const float*)d_in[0];  // h (32,50,50,128)
  const float* Wm      = (const float*)d_in[1];  // W (512,128)
  const float* att_src = (const float*)d_in[2];  // (32,16)
  const float* att_dst = (const float*)d_in[3];  // (32,16)
  const float* bias    = (const float*)d_in[4];  // (512,)
  float* out = (float*)d_out;

  float* PQ = (float*)d_ws;
  float* u  = PQ + 64 * 128;
  float* dv = u + (size_t)NB * NH * SAT;

  hipLaunchKernelGGL(k0_pq, dim3(32), dim3(256), 0, stream, Wm, att_src, att_dst, PQ);
  hipLaunchKernelGGL(k1_ud, dim3(1250), dim3(256), 0, stream, X, PQ, u, dv);
  hipLaunchKernelGGL(k2_attn, dim3(1024), dim3(512), 0, stream,
                     X, u, dv, Wm, bias, out);
}

// Round 11
// 287.284 us; speedup vs baseline: 1.2422x; 1.2422x over previous
//
#include <hip/hip_runtime.h>
#include <math.h>

// Problem constants
#define NA    50
#define NT    50
#define HIDK  128
#define NH    32
#define NC    16
#define NB    32
#define SAT   2500    // NA*NT
#define NS    2450    // (NA-1)*NT
#define NOUT  512     // NH*NC

// ============ K0: PQ[j][k] = sum_c att[j][c] * W[(j%32)*16+c][k] ============
__global__ __launch_bounds__(256) void k0_pq(const float* __restrict__ W,
                                             const float* __restrict__ att_src,
                                             const float* __restrict__ att_dst,
                                             float* __restrict__ PQ) {
  int g = blockIdx.x * 256 + threadIdx.x;   // 8192 total
  int j = g >> 7, k = g & 127;
  int hh = j & 31;
  const float* att = (j < 32) ? att_src : att_dst;
  float acc = 0.f;
  #pragma unroll
  for (int c = 0; c < 16; ++c)
    acc = fmaf(att[hh * 16 + c], W[(size_t)(hh * 16 + c) * 128 + k], acc);
  PQ[g] = acc;
}

// ============ K1: u[b][h][s] = x_row . p_h ; d[b][h][t] = x_ego_row . q_h ============
// k1 is permanent (R15 lesson: fusing re-reads X 32x from L2, bad trade).
__global__ __launch_bounds__(256) void k1_ud(
    const float* __restrict__ X,     // (80000,128)
    const float* __restrict__ PQ,    // (64,128)
    float* __restrict__ u,           // [b][h][2500]
    float* __restrict__ dv)          // [b][h][50]
{
  __shared__ float Ast[32][68];
  __shared__ float Bst[32][68];
  const int tid = threadIdx.x;
  const int m0 = blockIdx.x * 64;
  const int ty = tid >> 4, tx = tid & 15;
  float acc[4][4] = {};
  const int sr = tid >> 3, sc = tid & 7;

  for (int kc = 0; kc < 128; kc += 32) {
    #pragma unroll
    for (int L = 0; L < 2; ++L) {
      int row = sr + L * 32;
      float4 v = *(const float4*)&X[(size_t)(m0 + row) * 128 + kc + sc * 4];
      Ast[sc*4+0][row] = v.x; Ast[sc*4+1][row] = v.y;
      Ast[sc*4+2][row] = v.z; Ast[sc*4+3][row] = v.w;
      float4 w = *(const float4*)&PQ[(size_t)row * 128 + kc + sc * 4];
      Bst[sc*4+0][row] = w.x; Bst[sc*4+1][row] = w.y;
      Bst[sc*4+2][row] = w.z; Bst[sc*4+3][row] = w.w;
    }
    __syncthreads();
    #pragma unroll
    for (int k = 0; k < 32; ++k) {
      float4 a4 = *(const float4*)&Ast[k][ty * 4];
      float4 b4 = *(const float4*)&Bst[k][tx * 4];
      float a[4] = {a4.x, a4.y, a4.z, a4.w};
      float bb[4] = {b4.x, b4.y, b4.z, b4.w};
      #pragma unroll
      for (int i = 0; i < 4; ++i)
        #pragma unroll
        for (int j = 0; j < 4; ++j)
          acc[i][j] = fmaf(a[i], bb[j], acc[i][j]);
    }
    __syncthreads();
  }

  #pragma unroll
  for (int i = 0; i < 4; ++i) {
    int m = m0 + ty * 4 + i;
    int b = m / SAT, s = m - b * SAT;
    #pragma unroll
    for (int jj = 0; jj < 4; ++jj) {
      int col = tx * 4 + jj;
      if (col < 32)
        u[(size_t)(b * 32 + col) * SAT + s] = acc[i][jj];
      else if (s < NT)
        dv[(size_t)(b * 32 + col - 32) * NT + s] = acc[i][jj];
    }
  }
}

// ============ K2: bucket-decomposed attention in x-space ============
// R18: exact revert to R16 (291.9us, session best) after R17's P-space
// projection regressed (k2 110->177us: VALUBusy 50->28%, the 1632 fine-
// grained global-W dot products exposed latency; old scans+epilogue were
// NOT a bottleneck -- restructured a non-bottleneck). Confirmed-win set:
// R7 structure + fused fill + maxU fusion + shfl-scan + LPT stealing.
// After LPT no single phase dominates; k2 is distributed-latency-bound.
#define LOADG(B_, g_) do {                                                  \
    _Pragma("unroll")                                                       \
    for (int j = 0; j < 4; ++j) {                                           \
      int idx_ = base + 2 * ((g_) * 4 + j);                                 \
      e##B_[j] = sE[idx_]; s##B_[j] = sIdx[idx_];                           \
    }                                                                       \
    _Pragma("unroll")                                                       \
    for (int j = 0; j < 4; ++j)                                             \
      x##B_[j] = *(const float4*)(xb + (size_t)s##B_[j] * HIDK);            \
  } while (0)

#define COMPG(B_) do {                                                      \
    _Pragma("unroll")                                                       \
    for (int j = 0; j < 4; ++j) {                                           \
      float2 ee = e##B_[j]; float4 xx = x##B_[j];                           \
      a1[0]=fmaf(ee.x,xx.x,a1[0]); a1[1]=fmaf(ee.x,xx.y,a1[1]);             \
      a1[2]=fmaf(ee.x,xx.z,a1[2]); a1[3]=fmaf(ee.x,xx.w,a1[3]);             \
      a2[0]=fmaf(ee.y,xx.x,a2[0]); a2[1]=fmaf(ee.y,xx.y,a2[1]);             \
      a2[2]=fmaf(ee.y,xx.z,a2[2]); a2[3]=fmaf(ee.y,xx.w,a2[3]);             \
      z1 += ee.x; z2 += ee.y;                                               \
    }                                                                       \
  } while (0)

__global__ __launch_bounds__(512, 4) void k2_attn(
    const float* __restrict__ X,     // (32,2500,128)
    const float* __restrict__ u,     // [b][h][2500]
    const float* __restrict__ dv,    // [b][h][50]
    const float* __restrict__ W,     // (512,128)
    const float* __restrict__ bias,  // (512)
    float* __restrict__ out)
{
  const int id = blockIdx.x;
  const int b  = (id & 7) + 8 * (id >> 8);   // <=2 X-slices per XCD L2 window
  const int h  = (id >> 3) & 31;
  const int tid = threadIdx.x;

  __shared__ float Bb[2][51][129];   // [which][bucket][c]; c==128 = z   52.6 KB
  __shared__ float2 sE[NS];          // sorted (e1,e2)                   19.6 KB
  __shared__ unsigned short sIdx[NS];// sorted sat-index                  4.9 KB
  __shared__ float sTheta[50], sD[50], sF1[50], sF2[50];
  __shared__ int   sRank[50];
  __shared__ int   offs[52];
  __shared__ int   offCur[51];
  __shared__ int   segOrder[51];
  __shared__ int   segCtr;
  __shared__ float red[8];
  __shared__ float sMaxU;

  float* sU = &Bb[0][0][0];                       // alias (dead before F)
  unsigned short* sBeta = (unsigned short*)&Bb[1][0][0];  // alias (dead before F)

  const size_t bh = (size_t)b * 32 + h;
  const float* uP = u + bh * SAT + NT;   // skip ego rows

  // ---- load u (+ fused running max), dv ----
  float mx = -1e30f;
  for (int i = tid; i < NS; i += 512) { float v = uP[i]; sU[i] = v; mx = fmaxf(mx, v); }
  if (tid < 50) sD[tid] = dv[bh * NT + tid];
  if (tid < 51) offCur[tid] = 0;
  #pragma unroll
  for (int o = 32; o; o >>= 1) mx = fmaxf(mx, __shfl_xor(mx, o));
  if ((tid & 63) == 0) red[tid >> 6] = mx;
  __syncthreads();
  if (tid == 0) {
    float m2 = red[0];
    #pragma unroll
    for (int k = 1; k < 8; ++k) m2 = fmaxf(m2, red[k]);
    sMaxU = m2;
  }
  __syncthreads();
  const float maxU = sMaxU;

  // ---- theta rank-sort + per-query factors ----
  if (tid < 50) {
    float th = -sD[tid];
    int r = 0;
    for (int t2 = 0; t2 < 50; ++t2) {
      float th2 = -sD[t2];
      r += (th2 < th) || (th2 == th && t2 < tid);
    }
    sRank[tid] = r;
    sTheta[r] = th;
    float x = maxU + sD[tid];
    float L = (x >= 0.f) ? x : 0.2f * x;
    sF1[tid] = __expf(x - L);
    sF2[tid] = __expf(0.2f * x - L);
  }
  __syncthreads();

  // ---- histogram (store beta once; reuse in scatter) ----
  for (int i = tid; i < NS; i += 512) {
    float uu = sU[i];
    int lo = 0, hi = 50;
    while (lo < hi) { int mid = (lo + hi) >> 1; if (sTheta[mid] <= uu) lo = mid + 1; else hi = mid; }
    sBeta[i] = (unsigned short)lo;
    atomicAdd(&offCur[lo], 1);
  }
  __syncthreads();

  // ---- wave-0 parallel exclusive scan of 51 counts -> offs + offCur seed ----
  if (tid < 64) {
    int c = (tid < 51) ? offCur[tid] : 0;
    int inc = c;
    #pragma unroll
    for (int o = 1; o < 64; o <<= 1) {
      int n = __shfl_up(inc, o);
      if (tid >= o) inc += n;
    }
    if (tid < 51) { int ex = inc - c; offs[tid] = ex; offCur[tid] = ex; }
    if (tid == 50) offs[51] = inc;   // total = 2450
  }
  __syncthreads();

  // ---- scatter (all threads) + LPT segment sort (tid<51, overlapped) ----
  if (tid < 51) {
    int sz = offs[tid + 1] - offs[tid];
    int r = 0;
    for (int t2 = 0; t2 < 51; ++t2) {
      int sz2 = offs[t2 + 1] - offs[t2];
      r += (sz2 > sz) || (sz2 == sz && t2 < tid);
    }
    segOrder[r] = tid;    // descending size
  }
  if (tid == 511) segCtr = 0;
  for (int i = tid; i < NS; i += 512) {
    float uu = sU[i];
    int beta = sBeta[i];
    int pos = atomicAdd(&offCur[beta], 1);
    sE[pos] = make_float2(__expf(uu - maxU), __expf(0.2f * (uu - maxU)));
    sIdx[pos] = (unsigned short)(i + NT);
  }
  __syncthreads();

  // ---- F: LPT work-stealing, depth-2 software-pipelined gather ----
  {
    const int lane = tid & 63;
    const int slot = lane >> 5;       // which source of the pair
    const int cq   = lane & 31;       // channel quad cq*4..+3
    const float* xb = X + (size_t)b * SAT * HIDK + cq * 4;

    for (;;) {
      int kidx = 0;
      if (lane == 0) kidx = atomicAdd(&segCtr, 1);
      kidx = __shfl(kidx, 0);
      if (kidx >= 51) break;
      const int seg = segOrder[kidx];

      const int i0 = offs[seg], i1 = offs[seg + 1];
      const int base = i0 + slot;
      int np = i1 - base;                 // pairs this slot owns
      np = (np > 0) ? ((np + 1) >> 1) : 0;
      const int G = np >> 2;              // full groups of 4 pairs

      float a1[4] = {0.f, 0.f, 0.f, 0.f};
      float a2[4] = {0.f, 0.f, 0.f, 0.f};
      float z1 = 0.f, z2 = 0.f;

      float2 eA[4], eB[4]; int sA[4], sB[4]; float4 xA[4], xB[4];
      int g = 0;
      if (G) LOADG(A, 0);
      while (g + 2 <= G) {
        LOADG(B, g + 1);                  // prefetch next while computing cur
        COMPG(A);
        if (g + 2 < G) LOADG(A, g + 2);
        COMPG(B);
        g += 2;
      }
      if (g < G) COMPG(A);
      for (int k = G * 4; k < np; ++k) {  // remainder pairs
        int idx = base + 2 * k;
        float2 ee = sE[idx];
        int ss = sIdx[idx];
        float4 xx = *(const float4*)(xb + (size_t)ss * HIDK);
        a1[0]=fmaf(ee.x,xx.x,a1[0]); a1[1]=fmaf(ee.x,xx.y,a1[1]);
        a1[2]=fmaf(ee.x,xx.z,a1[2]); a1[3]=fmaf(ee.x,xx.w,a1[3]);
        a2[0]=fmaf(ee.y,xx.x,a2[0]); a2[1]=fmaf(ee.y,xx.y,a2[1]);
        a2[2]=fmaf(ee.y,xx.z,a2[2]); a2[3]=fmaf(ee.y,xx.w,a2[3]);
        z1 += ee.x; z2 += ee.y;
      }

      // combine the two slots; exclusive flush (no atomics, no zero-init)
      #pragma unroll
      for (int j = 0; j < 4; ++j) {
        a1[j] += __shfl_xor(a1[j], 32);
        a2[j] += __shfl_xor(a2[j], 32);
      }
      z1 += __shfl_xor(z1, 32);
      z2 += __shfl_xor(z2, 32);
      if (slot == 0) {
        #pragma unroll
        for (int j = 0; j < 4; ++j) {
          Bb[0][seg][cq * 4 + j] = a1[j];
          Bb[1][seg][cq * 4 + j] = a2[j];
        }
        if (cq == 0) { Bb[0][seg][128] = z1; Bb[1][seg][128] = z2; }
      }
    }
  }
  __syncthreads();

  // ---- stage W_h^T (aliases sE — dead after F) + scans ----
  float* WshT = (float*)sE;           // [128][16]
  const float* Wh = W + (size_t)h * 16 * 128;
  for (int v = tid; v < 2048; v += 512) {
    int k = v >> 4, cout = v & 15;
    WshT[k * 16 + cout] = Wh[(size_t)cout * 128 + k];
  }
  // scans over 51 buckets: which=0 -> exclusive suffix, which=1 -> inclusive prefix
  for (int task = tid; task < 258; task += 512) {
    int which = task >= 129;
    int c = task - which * 129;
    if (which == 0) {
      float run = 0.f;
      for (int k = 50; k >= 0; --k) { float tmp = Bb[0][k][c]; Bb[0][k][c] = run; run += tmp; }
    } else {
      float run = 0.f;
      for (int k = 0; k <= 50; ++k) { run += Bb[1][k][c]; Bb[1][k][c] = run; }
    }
  }
  __syncthreads();

  // ---- epilogue: project through W_h, divide, bias, store ego slice ----
  for (int task = tid; task < NT * NC; task += 512) {
    int t = task >> 4, cout = task & 15;
    int r = sRank[t];
    float F1 = sF1[t], F2 = sF2[t];
    float z = F1 * Bb[0][r][128] + F2 * Bb[1][r][128];
    const float* b1r = &Bb[0][r][0];
    const float* b2r = &Bb[1][r][0];
    float n1 = 0.f, n2 = 0.f;
    #pragma unroll 4
    for (int c = 0; c < 128; ++c) {
      float w = WshT[c * 16 + cout];
      n1 = fmaf(b1r[c], w, n1);
      n2 = fmaf(b2r[c], w, n2);
    }
    out[((size_t)b * SAT + t) * NOUT + h * 16 + cout] =
        (F1 * n1 + F2 * n2) / z + bias[h * 16 + cout];
  }

  // ---- fused bias fill of the non-ego region: fire-and-forget tail stores ----
  // 1024 blocks x 9800 float4 == 32 b x 313600 float4 (rows a>=1). Disjoint
  // from every block's ego-slice writes (a==0), so no barrier/race; stores
  // drain while other resident blocks compute. (proven R8-R16)
  {
    int g0 = id * 9800 + tid;
    const float4 b4 = ((const float4*)bias)[g0 & 127];  // constant per thread (stride 512 ≡ 0 mod 128)
    float4* o4 = (float4*)out;
    int gEnd = (id + 1) * 9800;
    for (int g = g0; g < gEnd; g += 512) {
      int bb2 = g / 313600;
      int o = g - bb2 * 313600;
      o4[(size_t)bb2 * 320000 + 6400 + o] = b4;
    }
  }
}

extern "C" void kernel_launch(void* const* d_in, const int* in_sizes, int n_in,
                              void* d_out, int out_size, void* d_ws, size_t ws_size,
                              hipStream_t stream) {
  const float* X       = (const float*)d_in[0];  // h (32,50,50,128)
  const float* Wm      = (const float*)d_in[1];  // W (512,128)
  const float* att_src = (const float*)d_in[2];  // (32,16)
  const float* att_dst = (const float*)d_in[3];  // (32,16)
  const float* bias    = (const float*)d_in[4];  // (512,)
  float* out = (float*)d_out;

  float* PQ = (float*)d_ws;
  float* u  = PQ + 64 * 128;
  float* dv = u + (size_t)NB * NH * SAT;

  hipLaunchKernelGGL(k0_pq, dim3(32), dim3(256), 0, stream, Wm, att_src, att_dst, PQ);
  hipLaunchKernelGGL(k1_ud, dim3(1250), dim3(256), 0, stream, X, PQ, u, dv);
  hipLaunchKernelGGL(k2_attn, dim3(1024), dim3(512), 0, stream,
                     X, u, dv, Wm, bias, out);
}

// Round 12
// 278.686 us; speedup vs baseline: 1.2806x; 1.0309x over previous
//
#include <hip/hip_runtime.h>
#include <math.h>

// Problem constants
#define NA    50
#define NT    50
#define HIDK  128
#define NH    32
#define NC    16
#define NB    32
#define SAT   2500    // NA*NT
#define NS    2450    // (NA-1)*NT
#define NOUT  512     // NH*NC

// ============ K0: PQ[j][k] = sum_c att[j][c] * W[(j%32)*16+c][k] ============
__global__ __launch_bounds__(256) void k0_pq(const float* __restrict__ W,
                                             const float* __restrict__ att_src,
                                             const float* __restrict__ att_dst,
                                             float* __restrict__ PQ) {
  int g = blockIdx.x * 256 + threadIdx.x;   // 8192 total
  int j = g >> 7, k = g & 127;
  int hh = j & 31;
  const float* att = (j < 32) ? att_src : att_dst;
  float acc = 0.f;
  #pragma unroll
  for (int c = 0; c < 16; ++c)
    acc = fmaf(att[hh * 16 + c], W[(size_t)(hh * 16 + c) * 128 + k], acc);
  PQ[g] = acc;
}

// ============ K1 v2: u[b][h][s] = x_row . p_h  (p-half ONLY) ============
// R19: old k1 computed the full N=64 product but the q-half (cols 32-63) is
// consumed at only 1600/80000 rows (dv). Half the FLOPs were discarded.
// Now: N=32 (p only), tile 128x32 per 256-thread block (same acc[4][4] and
// stage/inner structure as the proven k1, A-tile L=0..3), 625 blocks.
// dv moved into k2's preamble (50 ego-row dots, L2-resident X).
__global__ __launch_bounds__(256) void k1_u(
    const float* __restrict__ X,     // (80000,128)
    const float* __restrict__ PQ,    // (64,128); rows 0..31 = p_h
    float* __restrict__ u)           // [b][h][2500]
{
  __shared__ float Ast[32][132];
  __shared__ float Bst[32][36];
  const int tid = threadIdx.x;
  const int m0 = blockIdx.x * 128;
  const int ty = tid >> 3, tx = tid & 7;   // ty 0..31 (rows), tx 0..7 (cols)
  float acc[4][4] = {};
  const int sr = tid >> 3, sc = tid & 7;

  for (int kc = 0; kc < 128; kc += 32) {
    #pragma unroll
    for (int L = 0; L < 4; ++L) {
      int row = sr + L * 32;
      float4 v = *(const float4*)&X[(size_t)(m0 + row) * 128 + kc + sc * 4];
      Ast[sc*4+0][row] = v.x; Ast[sc*4+1][row] = v.y;
      Ast[sc*4+2][row] = v.z; Ast[sc*4+3][row] = v.w;
    }
    {
      float4 w = *(const float4*)&PQ[(size_t)sr * 128 + kc + sc * 4];
      Bst[sc*4+0][sr] = w.x; Bst[sc*4+1][sr] = w.y;
      Bst[sc*4+2][sr] = w.z; Bst[sc*4+3][sr] = w.w;
    }
    __syncthreads();
    #pragma unroll
    for (int k = 0; k < 32; ++k) {
      float4 a4 = *(const float4*)&Ast[k][ty * 4];
      float4 b4 = *(const float4*)&Bst[k][tx * 4];
      float a[4] = {a4.x, a4.y, a4.z, a4.w};
      float bb[4] = {b4.x, b4.y, b4.z, b4.w};
      #pragma unroll
      for (int i = 0; i < 4; ++i)
        #pragma unroll
        for (int j = 0; j < 4; ++j)
          acc[i][j] = fmaf(a[i], bb[j], acc[i][j]);
    }
    __syncthreads();
  }

  #pragma unroll
  for (int i = 0; i < 4; ++i) {
    int m = m0 + ty * 4 + i;
    int b = m / SAT, s = m - b * SAT;
    #pragma unroll
    for (int jj = 0; jj < 4; ++jj) {
      int col = tx * 4 + jj;
      u[(size_t)(b * 32 + col) * SAT + s] = acc[i][jj];
    }
  }
}

// ============ K2: bucket-decomposed attention in x-space ============
// R19: body = R18/R16 (287.3us best) byte-identical except the preamble:
// dv is now computed in-block (50 ego-row dots X[b,t,:].q_h; 400 threads x
// 16-ch partials + 8-lane shfl tree), overlapped with the u-load phase and
// done before the first barrier the theta-sort already waits on. Deletes
// the dv global round-trip. Confirmed-win set: R7 structure + fused fill +
// maxU fusion + shfl-scan + LPT stealing.
#define LOADG(B_, g_) do {                                                  \
    _Pragma("unroll")                                                       \
    for (int j = 0; j < 4; ++j) {                                           \
      int idx_ = base + 2 * ((g_) * 4 + j);                                 \
      e##B_[j] = sE[idx_]; s##B_[j] = sIdx[idx_];                           \
    }                                                                       \
    _Pragma("unroll")                                                       \
    for (int j = 0; j < 4; ++j)                                             \
      x##B_[j] = *(const float4*)(xb + (size_t)s##B_[j] * HIDK);            \
  } while (0)

#define COMPG(B_) do {                                                      \
    _Pragma("unroll")                                                       \
    for (int j = 0; j < 4; ++j) {                                           \
      float2 ee = e##B_[j]; float4 xx = x##B_[j];                           \
      a1[0]=fmaf(ee.x,xx.x,a1[0]); a1[1]=fmaf(ee.x,xx.y,a1[1]);             \
      a1[2]=fmaf(ee.x,xx.z,a1[2]); a1[3]=fmaf(ee.x,xx.w,a1[3]);             \
      a2[0]=fmaf(ee.y,xx.x,a2[0]); a2[1]=fmaf(ee.y,xx.y,a2[1]);             \
      a2[2]=fmaf(ee.y,xx.z,a2[2]); a2[3]=fmaf(ee.y,xx.w,a2[3]);             \
      z1 += ee.x; z2 += ee.y;                                               \
    }                                                                       \
  } while (0)

__global__ __launch_bounds__(512, 4) void k2_attn(
    const float* __restrict__ X,     // (32,2500,128)
    const float* __restrict__ u,     // [b][h][2500]
    const float* __restrict__ PQ,    // (64,128); rows 32..63 = q_h
    const float* __restrict__ W,     // (512,128)
    const float* __restrict__ bias,  // (512)
    float* __restrict__ out)
{
  const int id = blockIdx.x;
  const int b  = (id & 7) + 8 * (id >> 8);   // <=2 X-slices per XCD L2 window
  const int h  = (id >> 3) & 31;
  const int tid = threadIdx.x;

  __shared__ float Bb[2][51][129];   // [which][bucket][c]; c==128 = z   52.6 KB
  __shared__ float2 sE[NS];          // sorted (e1,e2)                   19.6 KB
  __shared__ unsigned short sIdx[NS];// sorted sat-index                  4.9 KB
  __shared__ float sTheta[50], sD[50], sF1[50], sF2[50];
  __shared__ int   sRank[50];
  __shared__ int   offs[52];
  __shared__ int   offCur[51];
  __shared__ int   segOrder[51];
  __shared__ int   segCtr;
  __shared__ float red[8];
  __shared__ float sMaxU;

  float* sU = &Bb[0][0][0];                       // alias (dead before F)
  unsigned short* sBeta = (unsigned short*)&Bb[1][0][0];  // alias (dead before F)

  const size_t bh = (size_t)b * 32 + h;
  const float* uP = u + bh * SAT + NT;   // skip ego rows
  const float* Xb = X + (size_t)b * SAT * HIDK;

  // ---- load u (+ fused running max); dv computed in-block ----
  float mx = -1e30f;
  for (int i = tid; i < NS; i += 512) { float v = uP[i]; sU[i] = v; mx = fmaxf(mx, v); }
  if (tid < 400) {
    // sD[t] = X[b, t, :] . q_h  (ego rows are flat sat rows 0..49)
    int row = tid >> 3, l = tid & 7;
    const float4* xr = (const float4*)(Xb + (size_t)row * HIDK + l * 16);
    const float4* qr = (const float4*)(PQ + (size_t)(32 + h) * 128 + l * 16);
    float acc = 0.f;
    #pragma unroll
    for (int c4 = 0; c4 < 4; ++c4) {
      float4 x = xr[c4], q = qr[c4];
      acc = fmaf(x.x, q.x, fmaf(x.y, q.y, fmaf(x.z, q.z, fmaf(x.w, q.w, acc))));
    }
    acc += __shfl_xor(acc, 1);
    acc += __shfl_xor(acc, 2);
    acc += __shfl_xor(acc, 4);
    if (l == 0) sD[row] = acc;
  }
  if (tid < 51) offCur[tid] = 0;
  #pragma unroll
  for (int o = 32; o; o >>= 1) mx = fmaxf(mx, __shfl_xor(mx, o));
  if ((tid & 63) == 0) red[tid >> 6] = mx;
  __syncthreads();
  if (tid == 0) {
    float m2 = red[0];
    #pragma unroll
    for (int k = 1; k < 8; ++k) m2 = fmaxf(m2, red[k]);
    sMaxU = m2;
  }
  __syncthreads();
  const float maxU = sMaxU;

  // ---- theta rank-sort + per-query factors ----
  if (tid < 50) {
    float th = -sD[tid];
    int r = 0;
    for (int t2 = 0; t2 < 50; ++t2) {
      float th2 = -sD[t2];
      r += (th2 < th) || (th2 == th && t2 < tid);
    }
    sRank[tid] = r;
    sTheta[r] = th;
    float x = maxU + sD[tid];
    float L = (x >= 0.f) ? x : 0.2f * x;
    sF1[tid] = __expf(x - L);
    sF2[tid] = __expf(0.2f * x - L);
  }
  __syncthreads();

  // ---- histogram (store beta once; reuse in scatter) ----
  for (int i = tid; i < NS; i += 512) {
    float uu = sU[i];
    int lo = 0, hi = 50;
    while (lo < hi) { int mid = (lo + hi) >> 1; if (sTheta[mid] <= uu) lo = mid + 1; else hi = mid; }
    sBeta[i] = (unsigned short)lo;
    atomicAdd(&offCur[lo], 1);
  }
  __syncthreads();

  // ---- wave-0 parallel exclusive scan of 51 counts -> offs + offCur seed ----
  if (tid < 64) {
    int c = (tid < 51) ? offCur[tid] : 0;
    int inc = c;
    #pragma unroll
    for (int o = 1; o < 64; o <<= 1) {
      int n = __shfl_up(inc, o);
      if (tid >= o) inc += n;
    }
    if (tid < 51) { int ex = inc - c; offs[tid] = ex; offCur[tid] = ex; }
    if (tid == 50) offs[51] = inc;   // total = 2450
  }
  __syncthreads();

  // ---- scatter (all threads) + LPT segment sort (tid<51, overlapped) ----
  if (tid < 51) {
    int sz = offs[tid + 1] - offs[tid];
    int r = 0;
    for (int t2 = 0; t2 < 51; ++t2) {
      int sz2 = offs[t2 + 1] - offs[t2];
      r += (sz2 > sz) || (sz2 == sz && t2 < tid);
    }
    segOrder[r] = tid;    // descending size
  }
  if (tid == 511) segCtr = 0;
  for (int i = tid; i < NS; i += 512) {
    float uu = sU[i];
    int beta = sBeta[i];
    int pos = atomicAdd(&offCur[beta], 1);
    sE[pos] = make_float2(__expf(uu - maxU), __expf(0.2f * (uu - maxU)));
    sIdx[pos] = (unsigned short)(i + NT);
  }
  __syncthreads();

  // ---- F: LPT work-stealing, depth-2 software-pipelined gather ----
  {
    const int lane = tid & 63;
    const int slot = lane >> 5;       // which source of the pair
    const int cq   = lane & 31;       // channel quad cq*4..+3
    const float* xb = Xb + cq * 4;

    for (;;) {
      int kidx = 0;
      if (lane == 0) kidx = atomicAdd(&segCtr, 1);
      kidx = __shfl(kidx, 0);
      if (kidx >= 51) break;
      const int seg = segOrder[kidx];

      const int i0 = offs[seg], i1 = offs[seg + 1];
      const int base = i0 + slot;
      int np = i1 - base;                 // pairs this slot owns
      np = (np > 0) ? ((np + 1) >> 1) : 0;
      const int G = np >> 2;              // full groups of 4 pairs

      float a1[4] = {0.f, 0.f, 0.f, 0.f};
      float a2[4] = {0.f, 0.f, 0.f, 0.f};
      float z1 = 0.f, z2 = 0.f;

      float2 eA[4], eB[4]; int sA[4], sB[4]; float4 xA[4], xB[4];
      int g = 0;
      if (G) LOADG(A, 0);
      while (g + 2 <= G) {
        LOADG(B, g + 1);                  // prefetch next while computing cur
        COMPG(A);
        if (g + 2 < G) LOADG(A, g + 2);
        COMPG(B);
        g += 2;
      }
      if (g < G) COMPG(A);
      for (int k = G * 4; k < np; ++k) {  // remainder pairs
        int idx = base + 2 * k;
        float2 ee = sE[idx];
        int ss = sIdx[idx];
        float4 xx = *(const float4*)(xb + (size_t)ss * HIDK);
        a1[0]=fmaf(ee.x,xx.x,a1[0]); a1[1]=fmaf(ee.x,xx.y,a1[1]);
        a1[2]=fmaf(ee.x,xx.z,a1[2]); a1[3]=fmaf(ee.x,xx.w,a1[3]);
        a2[0]=fmaf(ee.y,xx.x,a2[0]); a2[1]=fmaf(ee.y,xx.y,a2[1]);
        a2[2]=fmaf(ee.y,xx.z,a2[2]); a2[3]=fmaf(ee.y,xx.w,a2[3]);
        z1 += ee.x; z2 += ee.y;
      }

      // combine the two slots; exclusive flush (no atomics, no zero-init)
      #pragma unroll
      for (int j = 0; j < 4; ++j) {
        a1[j] += __shfl_xor(a1[j], 32);
        a2[j] += __shfl_xor(a2[j], 32);
      }
      z1 += __shfl_xor(z1, 32);
      z2 += __shfl_xor(z2, 32);
      if (slot == 0) {
        #pragma unroll
        for (int j = 0; j < 4; ++j) {
          Bb[0][seg][cq * 4 + j] = a1[j];
          Bb[1][seg][cq * 4 + j] = a2[j];
        }
        if (cq == 0) { Bb[0][seg][128] = z1; Bb[1][seg][128] = z2; }
      }
    }
  }
  __syncthreads();

  // ---- stage W_h^T (aliases sE — dead after F) + scans ----
  float* WshT = (float*)sE;           // [128][16]
  const float* Wh = W + (size_t)h * 16 * 128;
  for (int v = tid; v < 2048; v += 512) {
    int k = v >> 4, cout = v & 15;
    WshT[k * 16 + cout] = Wh[(size_t)cout * 128 + k];
  }
  // scans over 51 buckets: which=0 -> exclusive suffix, which=1 -> inclusive prefix
  for (int task = tid; task < 258; task += 512) {
    int which = task >= 129;
    int c = task - which * 129;
    if (which == 0) {
      float run = 0.f;
      for (int k = 50; k >= 0; --k) { float tmp = Bb[0][k][c]; Bb[0][k][c] = run; run += tmp; }
    } else {
      float run = 0.f;
      for (int k = 0; k <= 50; ++k) { run += Bb[1][k][c]; Bb[1][k][c] = run; }
    }
  }
  __syncthreads();

  // ---- epilogue: project through W_h, divide, bias, store ego slice ----
  for (int task = tid; task < NT * NC; task += 512) {
    int t = task >> 4, cout = task & 15;
    int r = sRank[t];
    float F1 = sF1[t], F2 = sF2[t];
    float z = F1 * Bb[0][r][128] + F2 * Bb[1][r][128];
    const float* b1r = &Bb[0][r][0];
    const float* b2r = &Bb[1][r][0];
    float n1 = 0.f, n2 = 0.f;
    #pragma unroll 4
    for (int c = 0; c < 128; ++c) {
      float w = WshT[c * 16 + cout];
      n1 = fmaf(b1r[c], w, n1);
      n2 = fmaf(b2r[c], w, n2);
    }
    out[((size_t)b * SAT + t) * NOUT + h * 16 + cout] =
        (F1 * n1 + F2 * n2) / z + bias[h * 16 + cout];
  }

  // ---- fused bias fill of the non-ego region: fire-and-forget tail stores ----
  // 1024 blocks x 9800 float4 == 32 b x 313600 float4 (rows a>=1). Disjoint
  // from every block's ego-slice writes (a==0), so no barrier/race; stores
  // drain while other resident blocks compute. (proven R8-R18)
  {
    int g0 = id * 9800 + tid;
    const float4 b4 = ((const float4*)bias)[g0 & 127];  // constant per thread (stride 512 ≡ 0 mod 128)
    float4* o4 = (float4*)out;
    int gEnd = (id + 1) * 9800;
    for (int g = g0; g < gEnd; g += 512) {
      int bb2 = g / 313600;
      int o = g - bb2 * 313600;
      o4[(size_t)bb2 * 320000 + 6400 + o] = b4;
    }
  }
}

extern "C" void kernel_launch(void* const* d_in, const int* in_sizes, int n_in,
                              void* d_out, int out_size, void* d_ws, size_t ws_size,
                              hipStream_t stream) {
  const float* X       = (const float*)d_in[0];  // h (32,50,50,128)
  const float* Wm      = (const float*)d_in[1];  // W (512,128)
  const float* att_src = (const float*)d_in[2];  // (32,16)
  const float* att_dst = (const float*)d_in[3];  // (32,16)
  const float* bias    = (const float*)d_in[4];  // (512,)
  float* out = (float*)d_out;

  float* PQ = (float*)d_ws;
  float* u  = PQ + 64 * 128;

  hipLaunchKernelGGL(k0_pq, dim3(32), dim3(256), 0, stream, Wm, att_src, att_dst, PQ);
  hipLaunchKernelGGL(k1_u, dim3(625), dim3(256), 0, stream, X, PQ, u);
  hipLaunchKernelGGL(k2_attn, dim3(1024), dim3(512), 0, stream,
                     X, u, PQ, Wm, bias, out);
}